// Round 6
// baseline (121.126 us; speedup 1.0000x reference)
//
#include <hip/hip_runtime.h>
#include <math.h>

typedef unsigned short u16t;
typedef __attribute__((ext_vector_type(8))) __bf16 bf16x8;
typedef __attribute__((ext_vector_type(4))) float f32x4;
typedef __attribute__((ext_vector_type(16))) float f32x16;
typedef __attribute__((ext_vector_type(4))) unsigned short u16x4;

__device__ __forceinline__ u16t f2bf(float f) {
  union { float f; unsigned u; } v; v.f = f;
  return (u16t)((v.u + 0x7FFFu + ((v.u >> 16) & 1u)) >> 16);
}

// async global->LDS, 16B per lane; LDS dest linear (wave-uniform base + lane*16)
__device__ __forceinline__ void gload_lds16(const void* g, void* l) {
  __builtin_amdgcn_global_load_lds(
      (__attribute__((address_space(1))) void*)(uintptr_t)g,
      (__attribute__((address_space(3))) void*)(unsigned)(uintptr_t)l,
      16, 0, 0);
}

// v_permlane32_swap_b32: exchanges half-wave words (verified mapping, rounds 4-5)
__device__ __forceinline__ void plswap(unsigned &a, unsigned &b) {
  asm("v_permlane32_swap_b32 %0, %1" : "+v"(a), "+v"(b));
}

// ---------------- fused f32 -> bf16 convert of target|source|value ----------------
__global__ __launch_bounds__(256) void k_cvt3(const float* __restrict__ t0,
                                              const float* __restrict__ s0,
                                              const float* __restrict__ v0,
                                              u16t* __restrict__ out) {
  int row = blockIdx.x, t = threadIdx.x;
  const float* src = row < 4096 ? t0 + ((size_t)row << 10)
                   : row < 6144 ? s0 + ((size_t)(row - 4096) << 10)
                                : v0 + ((size_t)(row - 6144) << 10);
  f32x4 x = *reinterpret_cast<const f32x4*>(src + t * 4);
  u16x4 y;
#pragma unroll
  for (int j = 0; j < 4; j++) y[j] = f2bf(x[j]);
  *reinterpret_cast<u16x4*>(out + ((size_t)row << 10) + t * 4) = y;
}

// ---------------- fused 4x weight transpose f32[1024][1024] -> bf16 transposed ----
__global__ __launch_bounds__(256) void k_wtrans4(const float* __restrict__ Wq,
                                                 const float* __restrict__ Wk,
                                                 const float* __restrict__ Wv,
                                                 const float* __restrict__ Wo,
                                                 u16t* __restrict__ dstAll) {
  __shared__ u16t tile[64][68];
  int z = blockIdx.z;
  const float* in = z == 0 ? Wq : z == 1 ? Wk : z == 2 ? Wv : Wo;
  u16t* out = dstAll + ((size_t)z << 20);
  int r0 = blockIdx.y * 64, c0 = blockIdx.x * 64;
  int t = threadIdx.x;
  int rr = t >> 4, q4 = (t & 15) * 4;
#pragma unroll
  for (int i = 0; i < 4; i++) {
    int r = rr + i * 16;
    f32x4 x = *reinterpret_cast<const f32x4*>(&in[(size_t)(r0 + r) * 1024 + c0 + q4]);
#pragma unroll
    for (int j = 0; j < 4; j++) tile[r][q4 + j] = f2bf(x[j]);
  }
  __syncthreads();
#pragma unroll
  for (int i = 0; i < 4; i++) {
    int c = rr + i * 16;
    u16x4 y;
#pragma unroll
    for (int j = 0; j < 4; j++) y[j] = tile[q4 + j][c];
    *reinterpret_cast<u16x4*>(&out[(size_t)(c0 + c) * 1024 + r0 + q4]) = y;
  }
}

// ---------------- bf16 transpose [2048][1024] -> [1024][2048] (V) ----------------
__global__ __launch_bounds__(256) void k_vtrans(const u16t* __restrict__ in,
                                                u16t* __restrict__ out) {
  __shared__ u16t tile[64][68];
  int r0 = blockIdx.y * 64, c0 = blockIdx.x * 64;
  int t = threadIdx.x;
  int rr = t >> 4, q4 = (t & 15) * 4;
#pragma unroll
  for (int i = 0; i < 4; i++) {
    int r = rr + i * 16;
    u16x4 x = *reinterpret_cast<const u16x4*>(&in[(size_t)(r0 + r) * 1024 + c0 + q4]);
#pragma unroll
    for (int j = 0; j < 4; j++) tile[r][q4 + j] = x[j];
  }
  __syncthreads();
#pragma unroll
  for (int i = 0; i < 4; i++) {
    int c = rr + i * 16;
    u16x4 y;
#pragma unroll
    for (int j = 0; j < 4; j++) y[j] = tile[q4 + j][c];
    *reinterpret_cast<u16x4*>(&out[(size_t)(c0 + c) * 2048 + r0 + q4]) = y;
  }
}

// ---------------- 128x128x(K=1024) MFMA core, 2-phase pipelined ----------------
__device__ __forceinline__ void gemm128_acc(const u16t* __restrict__ A,
                                            const u16t* __restrict__ Bt,
                                            int m0, int n0, f32x4 acc[4][4]) {
  __shared__ __align__(16) u16t As[2][128 * 64];
  __shared__ __align__(16) u16t Bs[2][128 * 64];
  int t = threadIdx.x, lane = t & 63, w = t >> 6;
  int l15 = lane & 15, l16 = lane >> 4;
  int wr = w >> 1, wc = w & 1;
  int srow = t >> 3;
  int slc = ((t & 7) ^ (srow & 7)) << 3;

#pragma unroll
  for (int i = 0; i < 4; i++) {
    int row = srow + i * 32;
    int c16 = (t + i * 256) * 16;
    gload_lds16(A + ((size_t)(m0 + row) << 10) + slc, (char*)As[0] + c16);
    gload_lds16(Bt + ((size_t)(n0 + row) << 10) + slc, (char*)Bs[0] + c16);
  }
  __syncthreads();

  for (int ki = 0; ki < 16; ki++) {
    int cur = ki & 1;
    if (ki < 15) {
      int kt = (ki + 1) << 6;
#pragma unroll
      for (int i = 0; i < 4; i++) {
        int row = srow + i * 32;
        int c16 = (t + i * 256) * 16;
        gload_lds16(A + ((size_t)(m0 + row) << 10) + kt + slc, (char*)As[cur ^ 1] + c16);
        gload_lds16(Bt + ((size_t)(n0 + row) << 10) + kt + slc, (char*)Bs[cur ^ 1] + c16);
      }
    }
#pragma unroll
    for (int kk = 0; kk < 2; kk++) {
      bf16x8 af[4], bfr[4];
#pragma unroll
      for (int m = 0; m < 4; m++) {
        int ar = wr * 64 + m * 16 + l15;
        af[m] = *(const bf16x8*)((char*)As[cur] + ar * 128 + ((kk * 64 + l16 * 16) ^ ((ar & 7) << 4)));
      }
#pragma unroll
      for (int n = 0; n < 4; n++) {
        int br = wc * 64 + n * 16 + l15;
        bfr[n] = *(const bf16x8*)((char*)Bs[cur] + br * 128 + ((kk * 64 + l16 * 16) ^ ((br & 7) << 4)));
      }
#pragma unroll
      for (int m = 0; m < 4; m++)
#pragma unroll
        for (int n = 0; n < 4; n++)
          acc[m][n] = __builtin_amdgcn_mfma_f32_16x16x32_bf16(af[m], bfr[n], acc[m][n], 0, 0, 0);
    }
    __syncthreads();
  }
}

// QKV GEMM with fused bias + ELU + per-head L2-norm epilogue -> bf16
__global__ __launch_bounds__(256) void k_gemm_qkv(const u16t* __restrict__ A,
                                                  const u16t* __restrict__ Wt,
                                                  const float* __restrict__ b0,
                                                  const float* __restrict__ b1,
                                                  const float* __restrict__ b2,
                                                  u16t* __restrict__ out) {
  int m0 = blockIdx.y * 128, n0 = blockIdx.x * 128;
  int seg = (m0 >= 6144) ? 2 : (m0 >= 4096) ? 1 : 0;
  const float* bias = (seg == 0) ? b0 : (seg == 1) ? b1 : b2;
  f32x4 acc[4][4] = {};
  gemm128_acc(A, Wt + ((size_t)seg << 20), m0, n0, acc);

  int t = threadIdx.x, lane = t & 63, w = t >> 6;
  int l15 = lane & 15, l16 = lane >> 4;
  int wr = w >> 1, wc = w & 1;
  float bb[4];
#pragma unroll
  for (int n = 0; n < 4; n++) bb[n] = bias[n0 + wc * 64 + n * 16 + l15];
  if (seg < 2) {
    float scale0 = (seg == 0) ? 0.125f : 1.f;
#pragma unroll
    for (int m = 0; m < 4; m++) {
#pragma unroll
      for (int r = 0; r < 4; r++) {
        float e[4]; float ss = 0.f;
#pragma unroll
        for (int n = 0; n < 4; n++) {
          float x = acc[m][n][r] + bb[n];
          e[n] = x > 0.f ? x : (__expf(x) - 1.f);
          ss += e[n] * e[n];
        }
        ss += __shfl_xor(ss, 1); ss += __shfl_xor(ss, 2);
        ss += __shfl_xor(ss, 4); ss += __shfl_xor(ss, 8);
        float rinv = rsqrtf(ss) * scale0;
        int row = m0 + wr * 64 + m * 16 + l16 * 4 + r;
#pragma unroll
        for (int n = 0; n < 4; n++)
          out[((size_t)row << 10) + n0 + wc * 64 + n * 16 + l15] = f2bf(e[n] * rinv);
      }
    }
  } else {
#pragma unroll
    for (int m = 0; m < 4; m++) {
      int row = m0 + wr * 64 + m * 16 + l16 * 4;
#pragma unroll
      for (int n = 0; n < 4; n++) {
        int col = n0 + wc * 64 + n * 16 + l15;
#pragma unroll
        for (int r = 0; r < 4; r++)
          out[((size_t)(row + r) << 10) + col] = f2bf(acc[m][n][r] + bb[n]);
      }
    }
  }
}

// O-projection GEMM: ctx bf16 @ Wo^T + bo -> f32
__global__ __launch_bounds__(256) void k_gemm_o(const u16t* __restrict__ A,
                                                const u16t* __restrict__ Wt,
                                                const float* __restrict__ bias,
                                                float* __restrict__ C) {
  int m0 = blockIdx.y * 128, n0 = blockIdx.x * 128;
  f32x4 acc[4][4] = {};
  gemm128_acc(A, Wt, m0, n0, acc);
  int t = threadIdx.x, lane = t & 63, w = t >> 6;
  int l15 = lane & 15, l16 = lane >> 4;
  int wr = w >> 1, wc = w & 1;
#pragma unroll
  for (int n = 0; n < 4; n++) {
    int col = n0 + wc * 64 + n * 16 + l15;
    float bb = bias[col];
#pragma unroll
    for (int m = 0; m < 4; m++) {
      int row = m0 + wr * 64 + m * 16 + l16 * 4;
#pragma unroll
      for (int r = 0; r < 4; r++)
        C[((size_t)(row + r) << 10) + col] = acc[m][n][r] + bb;
    }
  }
}

// ---------------- fused attention v3 ----------------
// 2 waves x 64 q = 128 q/block; grid (16,32). Per-wave private dbuf K/V staging,
// NO barriers (wave-local vmcnt sync). 40 MFMA 32x32x16 per chunk per wave.
// P via cvt_pk + permlane32_swap (in-register); rsum via ones-MFMA.
__global__ __launch_bounds__(128) void k_attn(const u16t* __restrict__ qn,
                                              const u16t* __restrict__ kn,
                                              const u16t* __restrict__ vT,
                                              u16t* __restrict__ ctx) {
  __shared__ __align__(16) char lds[2][32768];   // per wave: 2 bufs x (K 8KB | V 8KB)
  int bh = blockIdx.y, b = bh >> 4, h = bh & 15;
  int qt = blockIdx.x;
  int t = threadIdx.x, lane = t & 63, w = t >> 6;
  int l31 = lane & 31, hi = lane >> 5;
  char* wbase = lds[w];

  // Q B-frags: qf[qtile][ks]; qn pre-scaled by 0.125 in QKV epilogue
  const u16t* qp0 = qn + ((size_t)(b * 2048 + qt * 128 + w * 64 + l31) << 10) + (h << 6) + hi * 8;
  bf16x8 qf[2][4];
#pragma unroll
  for (int q2 = 0; q2 < 2; q2++)
#pragma unroll
    for (int ks = 0; ks < 4; ks++)
      qf[q2][ks] = *(const bf16x8*)(qp0 + (q2 << 15) + ks * 16);

  union { unsigned u[4]; bf16x8 v; } onesu;
  onesu.u[0] = onesu.u[1] = onesu.u[2] = onesu.u[3] = 0x3F803F80u;
  const bf16x8 ones = onesu.v;
  const f32x16 fz = {};

  // staging source offsets (lane-invariant across chunks)
  int r8 = lane >> 3, c8 = lane & 7;
  int sce = (c8 ^ (r8 & 7)) << 3;                       // pre-swizzled element offset
  const u16t* kbasep = kn + r8 * 1024 + (h << 6) + sce; // + ku + j*8192
  const u16t* vbasep = vT + ((size_t)(h * 64 + r8) << 11) + sce; // + vu + j*16384
  int ldst = lane << 4;

  // frag read vaddrs (shared by K and V via static imm offsets)
  int kxor = (l31 & 7) << 4;
  int va0[4], va1[4];
#pragma unroll
  for (int ks = 0; ks < 4; ks++) {
    int off = (ks * 32 + hi * 16) ^ kxor;
    va0[ks] = l31 * 128 + off;
    va1[ks] = (32 + l31) * 128 + off;
  }

  f32x16 o00 = {}, o01 = {}, o10 = {}, o11 = {}, rs0 = {}, rs1 = {};

#define MF32(A, B, C) __builtin_amdgcn_mfma_f32_32x32x16_bf16(A, B, C, 0, 0, 0)

#define STAGE(IT1, NB) do {                                                  \
    int ku_ = ((IT1) & 31) << 16;                                            \
    int vu_ = ((IT1) & 31) << 6;                                             \
    char* db_ = wbase + (NB) * 16384;                                        \
    _Pragma("unroll")                                                        \
    for (int j = 0; j < 8; j++)                                              \
      gload_lds16(kbasep + ku_ + j * 8192, db_ + ldst + j * 1024);           \
    _Pragma("unroll")                                                        \
    for (int j = 0; j < 8; j++)                                              \
      gload_lds16(vbasep + vu_ + j * 16384, db_ + 8192 + ldst + j * 1024);   \
  } while (0)

#define EXPPACK(S, FA, FB) do {                                              \
    unsigned mm[8];                                                          \
    _Pragma("unroll")                                                        \
    for (int i = 0; i < 8; i++) {                                            \
      float pa_ = fmaf(S[2 * i], fmaf(S[2 * i], 0.5f, 1.f), 1.f);            \
      float pb_ = fmaf(S[2 * i + 1], fmaf(S[2 * i + 1], 0.5f, 1.f), 1.f);    \
      asm("v_cvt_pk_bf16_f32 %0, %1, %2" : "=v"(mm[i]) : "v"(pa_), "v"(pb_));\
    }                                                                        \
    plswap(mm[0], mm[2]); plswap(mm[1], mm[3]);                              \
    plswap(mm[4], mm[6]); plswap(mm[5], mm[7]);                              \
    union { unsigned u[4]; bf16x8 v; } A_, B_;                               \
    A_.u[0] = mm[0]; A_.u[1] = mm[1]; A_.u[2] = mm[2]; A_.u[3] = mm[3];      \
    B_.u[0] = mm[4]; B_.u[1] = mm[5]; B_.u[2] = mm[6]; B_.u[3] = mm[7];      \
    FA = A_.v; FB = B_.v;                                                    \
  } while (0)

#define CHUNK(IT, CUR) do {                                                  \
    asm volatile("s_waitcnt vmcnt(0)" ::: "memory");                         \
    const char* kb_ = wbase + (CUR) * 16384;                                 \
    f32x16 s00, s01, s10, s11;                                               \
    _Pragma("unroll")                                                        \
    for (int ks = 0; ks < 4; ks++) {                                         \
      bf16x8 a0_ = *(const bf16x8*)(kb_ + va0[ks]);                          \
      bf16x8 a1_ = *(const bf16x8*)(kb_ + va1[ks]);                          \
      s00 = MF32(a0_, qf[0][ks], ks == 0 ? fz : s00);                        \
      s01 = MF32(a0_, qf[1][ks], ks == 0 ? fz : s01);                        \
      s10 = MF32(a1_, qf[0][ks], ks == 0 ? fz : s10);                        \
      s11 = MF32(a1_, qf[1][ks], ks == 0 ? fz : s11);                        \
    }                                                                        \
    bf16x8 pf0[4], pf1[4];                                                   \
    EXPPACK(s00, pf0[0], pf0[1]); EXPPACK(s10, pf0[2], pf0[3]);              \
    EXPPACK(s01, pf1[0], pf1[1]); EXPPACK(s11, pf1[2], pf1[3]);              \
    bf16x8 v0_[4], v1_[4];                                                   \
    _Pragma("unroll")                                                        \
    for (int ks = 0; ks < 4; ks++) {                                         \
      v0_[ks] = *(const bf16x8*)(kb_ + 8192 + va0[ks]);                      \
      v1_[ks] = *(const bf16x8*)(kb_ + 8192 + va1[ks]);                      \
    }                                                                        \
    STAGE((IT) + 1, (CUR) ^ 1);                                              \
    __builtin_amdgcn_s_setprio(1);                                           \
    _Pragma("unroll")                                                        \
    for (int ks = 0; ks < 4; ks++) {                                         \
      o00 = MF32(pf0[ks], v0_[ks], o00);                                     \
      o01 = MF32(pf0[ks], v1_[ks], o01);                                     \
      o10 = MF32(pf1[ks], v0_[ks], o10);                                     \
      o11 = MF32(pf1[ks], v1_[ks], o11);                                     \
      rs0 = MF32(pf0[ks], ones, rs0);                                        \
      rs1 = MF32(pf1[ks], ones, rs1);                                        \
    }                                                                        \
    __builtin_amdgcn_s_setprio(0);                                           \
  } while (0)

  STAGE(0, 0);
  for (int ii = 0; ii < 16; ++ii) {
    CHUNK(2 * ii, 0);
    CHUNK(2 * ii + 1, 1);
  }

  // epilogue: divide by rsum (same C-layout) and store
  size_t rbase = (size_t)(b * 2048 + qt * 128 + w * 64);
#pragma unroll
  for (int r = 0; r < 16; r++) {
    int q = (r & 3) + 8 * (r >> 2) + 4 * hi;
    float ri0 = 1.f / rs0[r];
    float ri1 = 1.f / rs1[r];
    u16t* cp0 = ctx + ((rbase + q) << 10) + (h << 6) + l31;
    u16t* cp1 = ctx + ((rbase + 32 + q) << 10) + (h << 6) + l31;
    cp0[0]  = f2bf(o00[r] * ri0);
    cp0[32] = f2bf(o01[r] * ri0);
    cp1[0]  = f2bf(o10[r] * ri1);
    cp1[32] = f2bf(o11[r] * ri1);
  }
#undef CHUNK
#undef EXPPACK
#undef STAGE
#undef MF32
}

// ---------------- residual + LayerNorm ----------------
__global__ __launch_bounds__(256) void k_out_ln(const float* __restrict__ Hh,
                                                const float* __restrict__ target,
                                                const float* __restrict__ g,
                                                const float* __restrict__ bb,
                                                float* __restrict__ out) {
  __shared__ float s_s[4], s_ss[4];
  int row = blockIdx.x, t = threadIdx.x, w = t >> 6;
  f32x4 hv = *reinterpret_cast<const f32x4*>(&Hh[(size_t)row * 1024 + t * 4]);
  f32x4 tv = *reinterpret_cast<const f32x4*>(&target[(size_t)row * 1024 + t * 4]);
  f32x4 x;
#pragma unroll
  for (int j = 0; j < 4; j++) x[j] = hv[j] + tv[j];
  float s = x[0] + x[1] + x[2] + x[3];
  float ss = x[0] * x[0] + x[1] * x[1] + x[2] * x[2] + x[3] * x[3];
#pragma unroll
  for (int m = 1; m < 64; m <<= 1) { s += __shfl_xor(s, m); ss += __shfl_xor(ss, m); }
  if ((t & 63) == 0) { s_s[w] = s; s_ss[w] = ss; }
  __syncthreads();
  s = s_s[0] + s_s[1] + s_s[2] + s_s[3];
  ss = s_ss[0] + s_ss[1] + s_ss[2] + s_ss[3];
  float mu = s * (1.f / 1024.f);
  float var = ss * (1.f / 1024.f) - mu * mu;
  float rsn = rsqrtf(var + 1e-12f);
  f32x4 gv = *reinterpret_cast<const f32x4*>(&g[t * 4]);
  f32x4 bv = *reinterpret_cast<const f32x4*>(&bb[t * 4]);
  f32x4 o;
#pragma unroll
  for (int j = 0; j < 4; j++) o[j] = (x[j] - mu) * rsn * gv[j] + bv[j];
  *reinterpret_cast<f32x4*>(&out[(size_t)row * 1024 + t * 4]) = o;
}

extern "C" void kernel_launch(void* const* d_in, const int* in_sizes, int n_in,
                              void* d_out, int out_size, void* d_ws, size_t ws_size,
                              hipStream_t stream) {
  const float* target = (const float*)d_in[0];
  const float* source = (const float*)d_in[1];
  const float* value  = (const float*)d_in[2];
  const float* Wq = (const float*)d_in[3];
  const float* bq = (const float*)d_in[4];
  const float* Wk = (const float*)d_in[5];
  const float* bk = (const float*)d_in[6];
  const float* Wv = (const float*)d_in[7];
  const float* bvp = (const float*)d_in[8];
  const float* Wo = (const float*)d_in[9];
  const float* bo = (const float*)d_in[10];
  const float* lng = (const float*)d_in[11];
  const float* lnb = (const float*)d_in[12];
  float* out = (float*)d_out;
  char* ws = (char*)d_ws;
  const size_t MB = 1u << 20;

  u16t* abf   = (u16t*)ws;                       // [0,16) bf16 target|source|value
  u16t* Wt    = (u16t*)(ws + 16 * MB);           // [16,24) 4x transposed weights
  u16t* Wot   = Wt + ((size_t)3 << 20);
  u16t* qkvnb = (u16t*)(ws + 24 * MB);           // [24,40) qn|kn|vbf
  u16t* qnb   = qkvnb;
  u16t* knb   = qkvnb + ((size_t)4096 << 10);
  u16t* vbf   = qkvnb + ((size_t)6144 << 10);
  u16t* vTb   = (u16t*)(ws + 40 * MB);           // [40,44) vT [1024][2048]
  u16t* ctxb  = (u16t*)(ws + 44 * MB);           // [44,52)
  float* Hf   = (float*)(ws + 52 * MB);          // [52,68)

  k_cvt3<<<dim3(8192), 256, 0, stream>>>(target, source, value, abf);
  k_wtrans4<<<dim3(16, 16, 4), 256, 0, stream>>>(Wq, Wk, Wv, Wo, Wt);
  k_gemm_qkv<<<dim3(8, 64), 256, 0, stream>>>(abf, Wt, bq, bk, bvp, qkvnb);
  k_vtrans<<<dim3(16, 32), 256, 0, stream>>>(vbf, vTb);
  k_attn<<<dim3(16, 32), 128, 0, stream>>>(qnb, knb, vTb, ctxb);
  k_gemm_o<<<dim3(8, 32), 256, 0, stream>>>(ctxb, Wot, bo, Hf);
  k_out_ln<<<dim3(4096), 256, 0, stream>>>(Hf, target, lng, lnb, out);
}